// Round 12
// baseline (213.555 us; speedup 1.0000x reference)
//
#include <hip/hip_runtime.h>

typedef __attribute__((ext_vector_type(8))) _Float16 half8;
typedef __attribute__((ext_vector_type(4))) _Float16 half4v;
typedef __attribute__((ext_vector_type(4))) float floatx4;

#define NB 128
#define NN 64
#define NV 14
#define PP 32
#define SS 14
#define HH 128
#define DE 64
#define NCLS 5
#define PITCH 136   // halves; used by node_out only

// fragment-major weight offsets (halves). layout: [nt][ks][lane][8]
#define OFF_W2   0
#define OFF_W3   16384
#define OFF_W2PV 24576
#define OFF_W3PV 40960
#define OFF_FO1  49152
#define OFF_FO2  69632
#define OFF_FO3  86016

__device__ __forceinline__ floatx4 MFMA(half8 a, half8 b, floatx4 c) {
  return __builtin_amdgcn_mfma_f32_16x16x32_f16(a, b, c, 0, 0, 0);
}

// ---------------- K0: fp16 layer-1 terms (+bias fold), frag-major weights, d_out zero ----------------
__global__ __launch_bounds__(256) void k0_prep(
    const float* __restrict__ x, const float* __restrict__ y,
    const float* __restrict__ fr1_w, const float* __restrict__ fr1_b,
    const float* __restrict__ fr1pv_w, const float* __restrict__ fr1pv_b,
    const float* __restrict__ fr2_w, const float* __restrict__ fr3_w,
    const float* __restrict__ fr2pv_w, const float* __restrict__ fr3pv_w,
    const float* __restrict__ fo1_w, const float* __restrict__ fo2_w,
    const float* __restrict__ fo3_w,
    _Float16* __restrict__ A1h, _Float16* __restrict__ B1h,
    _Float16* __restrict__ A1pvh, _Float16* __restrict__ B1pvh,
    _Float16* __restrict__ WT, float* __restrict__ dout) {
  int blk = blockIdx.x;
  int tid = threadIdx.x;
  if (blk < 768) {
    int mat = blk >> 8, sub = blk & 255;
    int b = sub >> 1, n0 = (sub & 1) << 5;
    __shared__ float sxT[32 * 33];
    for (int i = tid; i < 32 * PP; i += 256) {
      int p = i >> 5, n = i & 31;
      sxT[n * 33 + p] = x[b * (PP * NN) + p * 64 + n0 + n];
    }
    __syncthreads();
    const float* w; _Float16* outp; const float* bias;
    if (mat == 0)      { w = fr1_w;           outp = A1h;   bias = fr1_b; }
    else if (mat == 1) { w = fr1_w + 32 * HH; outp = B1h;   bias = nullptr; }
    else               { w = fr1pv_w;         outp = A1pvh; bias = fr1pv_b; }
    for (int o = tid; o < 32 * 32; o += 256) {
      int n = o >> 5, jc = o & 31;
      float4 acc = {0.f, 0.f, 0.f, 0.f};
      const float* xr = &sxT[n * 33];
#pragma unroll 8
      for (int k = 0; k < PP; k++) {
        float xv = xr[k];
        float4 wv = ((const float4*)w)[k * 32 + jc];
        acc.x += xv * wv.x; acc.y += xv * wv.y;
        acc.z += xv * wv.z; acc.w += xv * wv.w;
      }
      if (bias) {
        float4 bv = ((const float4*)bias)[jc];
        acc.x += bv.x; acc.y += bv.y; acc.z += bv.z; acc.w += bv.w;
      }
      half4v hv;
      hv[0] = (_Float16)acc.x; hv[1] = (_Float16)acc.y;
      hv[2] = (_Float16)acc.z; hv[3] = (_Float16)acc.w;
      *(half4v*)(&outp[(b * NN + n0 + n) * HH + jc * 4]) = hv;
    }
  } else if (blk < 896) {
    int b = blk - 768;
    __shared__ float syT[NV * 15];
    for (int i = tid; i < SS * NV; i += 256) {
      int s = i / NV, v = i - s * NV;
      syT[v * 15 + s] = y[b * (SS * NV) + i];
    }
    __syncthreads();
    const float4* w4 = (const float4*)(fr1pv_w + 32 * HH);
    for (int o = tid; o < NV * 32; o += 256) {
      int v = o >> 5, jc = o & 31;
      float4 acc = {0.f, 0.f, 0.f, 0.f};
#pragma unroll
      for (int s = 0; s < SS; s++) {
        float yv = syT[v * 15 + s];
        float4 wv = w4[s * 32 + jc];
        acc.x += yv * wv.x; acc.y += yv * wv.y;
        acc.z += yv * wv.z; acc.w += yv * wv.w;
      }
      half4v hv;
      hv[0] = (_Float16)acc.x; hv[1] = (_Float16)acc.y;
      hv[2] = (_Float16)acc.z; hv[3] = (_Float16)acc.w;
      *(half4v*)(&B1pvh[(b * NV + v) * HH + jc * 4]) = hv;
    }
  } else if (blk < 925) {
    // frag-major transform, one block per (matrix, ks):
    // dst[((nt*NKS+ks)*64 + l)*8 + j] = src[(ks*32 + qq*8 + j)*N + nt*16 + cc]
    int t = blk - 896;
    int wid, ks;
    if (t < 16)      { wid = t >> 2; ks = t & 3; }
    else if (t < 21) { wid = 4; ks = t - 16; }
    else if (t < 25) { wid = 5; ks = t - 21; }
    else             { wid = 6; ks = t - 25; }
    const float* src; int N, NKS, NTN; _Float16* dst;
    switch (wid) {
      case 0: src = fr2_w;   N = 128; NKS = 4; NTN = 8; dst = WT + OFF_W2;   break;
      case 1: src = fr3_w;   N = 64;  NKS = 4; NTN = 4; dst = WT + OFF_W3;   break;
      case 2: src = fr2pv_w; N = 128; NKS = 4; NTN = 8; dst = WT + OFF_W2PV; break;
      case 3: src = fr3pv_w; N = 64;  NKS = 4; NTN = 4; dst = WT + OFF_W3PV; break;
      case 4: src = fo1_w;   N = 128; NKS = 5; NTN = 8; dst = WT + OFF_FO1;  break;
      case 5: src = fo2_w;   N = 128; NKS = 4; NTN = 8; dst = WT + OFF_FO2;  break;
      default: src = fo3_w;  N = 64;  NKS = 4; NTN = 4; dst = WT + OFF_FO3;  break;
    }
    __shared__ float sw[32 * 132];   // 32 rows x (N<=128, +4 pad) = 16.5 KB
    int NP = N + 4;
    int n4 = N >> 2;
    for (int i = tid; i < 32 * n4; i += 256) {
      int row = i / n4, c4 = i - row * n4;
      *(float4*)(&sw[row * NP + c4 * 4]) = *(const float4*)(&src[(ks * 32 + row) * N + c4 * 4]);
    }
    __syncthreads();
    for (int o = tid; o < NTN * 64; o += 256) {
      int nt = o >> 6, l = o & 63;
      int cc = l & 15, qq = l >> 4;
      half8 hv;
#pragma unroll
      for (int j = 0; j < 8; j++) hv[j] = (_Float16)sw[(qq * 8 + j) * NP + nt * 16 + cc];
      *(half8*)(&dst[((nt * NKS + ks) * 64 + l) << 3]) = hv;
    }
  } else {
    for (int i = tid; i < NB * NCLS; i += 256) dout[i] = 0.f;
  }
}

// ---------------- fused EDGE kernel: receiver-major + UNIFORM 32-tile blocks, 5/CU ----------------
// r11 post-mortem: occupancy 24.8% = pv blocks (half a pp block's work) idling their CU slot
// for the kernel's second half. This round: every block = 32 tiles exactly.
//   pp: 1024 blocks x 8 receivers (2/wave, 4 tiles each); pv: 256 blocks x 32 k-nodes
//   (8/wave, 1 tile each). 1280 blocks = exactly 5 x 256 CUs, ALL resident (LDS = 32768 B
//   exactly: W2 nt0-3 in LDS 16 KB + sH slices 16 KB; W2 nt4-7 + biases from global, L1-hot,
//   z0-laundered). 20 free-drifting waves/CU (2.1x r11's average).
__device__ __forceinline__ void pp_wave(
    const _Float16* __restrict__ Arow, const _Float16* __restrict__ Bb,
    const _Float16* sW2, const _Float16* __restrict__ w2g,
    const _Float16* __restrict__ w3g,
    const float* __restrict__ b2g, const float* __restrict__ b3g,
    _Float16* sH, int r, int lane, float* __restrict__ outp) {
  int c = lane & 15, q = lane >> 4;
  half8 av[4];
#pragma unroll
  for (int ks = 0; ks < 4; ks++)
    av[ks] = *(const half8*)(Arow + ks * 32 + q * 8);
  floatx4 regS = {0.f, 0.f, 0.f, 0.f};
#pragma unroll 1
  for (int tp = 0; tp < 2; tp++) {
    int z0 = 0;
    asm volatile("" : "+v"(z0));   // defeats LICM of W2-hi/W3/bias loads across iterations
    int tb0 = tp * 32, tb1 = tb0 + 16;
    int jj0 = tb0 + c; if (jj0 > 62) jj0 = 62;
    int s0 = jj0 + (jj0 >= r ? 1 : 0);
    int jj1 = tb1 + c; if (jj1 > 62) jj1 = 62;
    int s1 = jj1 + (jj1 >= r ? 1 : 0);
    const _Float16* b0p = Bb + s0 * HH;
    const _Float16* b1p = Bb + s1 * HH;
    floatx4 acc0[8], acc1[8];
#pragma unroll
    for (int nt = 0; nt < 8; nt++) {
      acc0[nt] = (floatx4){0.f, 0.f, 0.f, 0.f};
      acc1[nt] = (floatx4){0.f, 0.f, 0.f, 0.f};
    }
#pragma unroll
    for (int ks = 0; ks < 4; ks++) {
      half8 bv0 = *(const half8*)(b0p + ks * 32 + q * 8);
      half8 bv1 = *(const half8*)(b1p + ks * 32 + q * 8);
      half8 h0 = av[ks] + bv0;
      half8 h1 = av[ks] + bv1;
#pragma unroll
      for (int j = 0; j < 8; j++) {
        h0[j] = h0[j] > (_Float16)0.f ? h0[j] : (_Float16)0.f;
        h1[j] = h1[j] > (_Float16)0.f ? h1[j] : (_Float16)0.f;
      }
#pragma unroll
      for (int nt = 0; nt < 8; nt++) {
        half8 w;
        if (nt < 4) w = *(const half8*)(&sW2[((nt * 4 + ks) << 9) + (lane << 3)]);
        else        w = *(const half8*)(&w2g[z0 + ((nt * 4 + ks) << 9) + (lane << 3)]);
        acc0[nt] = MFMA(w, h0, acc0[nt]);
        acc1[nt] = MFMA(w, h1, acc1[nt]);
      }
    }
    // L2 epilogue: tile0 -> sH now, tile1 parks in regs (time-shared slice, r7)
    half4v g1r[8];
#pragma unroll
    for (int nt = 0; nt < 8; nt++) {
      float4 bbt = *(const float4*)(&b2g[z0 + nt * 16 + q * 4]);
      half4v g0, g1;
      g0[0] = (_Float16)fmaxf(acc0[nt][0] + bbt.x, 0.f);
      g0[1] = (_Float16)fmaxf(acc0[nt][1] + bbt.y, 0.f);
      g0[2] = (_Float16)fmaxf(acc0[nt][2] + bbt.z, 0.f);
      g0[3] = (_Float16)fmaxf(acc0[nt][3] + bbt.w, 0.f);
      g1[0] = (_Float16)fmaxf(acc1[nt][0] + bbt.x, 0.f);
      g1[1] = (_Float16)fmaxf(acc1[nt][1] + bbt.y, 0.f);
      g1[2] = (_Float16)fmaxf(acc1[nt][2] + bbt.z, 0.f);
      g1[3] = (_Float16)fmaxf(acc1[nt][3] + bbt.w, 0.f);
      int slot = ((nt << 1) + (q >> 1)) ^ c;
      int addr = (c << 7) + (slot << 3) + ((q & 1) << 2);
      *(half4v*)(&sH[addr]) = g0;
      g1r[nt] = g1;
    }
    half8 a20[4], a21[4];
#pragma unroll
    for (int ks = 0; ks < 4; ks++) {
      int addr = (c << 7) + ((((ks << 2) + q) ^ c) << 3);
      a20[ks] = *(const half8*)(&sH[addr]);
    }
#pragma unroll
    for (int nt = 0; nt < 8; nt++) {
      int slot = ((nt << 1) + (q >> 1)) ^ c;
      int addr = (c << 7) + (slot << 3) + ((q & 1) << 2);
      *(half4v*)(&sH[addr]) = g1r[nt];
    }
#pragma unroll
    for (int ks = 0; ks < 4; ks++) {
      int addr = (c << 7) + ((((ks << 2) + q) ^ c) << 3);
      a21[ks] = *(const half8*)(&sH[addr]);
    }
    // L3: shared W3 loads feed both tiles; masked accumulate into regS
#pragma unroll
    for (int nt3 = 0; nt3 < 4; nt3++) {
      floatx4 e0 = {0.f, 0.f, 0.f, 0.f};
      floatx4 e1 = {0.f, 0.f, 0.f, 0.f};
#pragma unroll
      for (int ks = 0; ks < 4; ks++) {
        half8 wf = *(const half8*)(&w3g[z0 + ((nt3 * 4 + ks) << 9) + (lane << 3)]);
        e0 = MFMA(a20[ks], wf, e0);
        e1 = MFMA(a21[ks], wf, e1);
      }
      float b3v = b3g[z0 + nt3 * 16 + c];
      int rb0 = tb0 + q * 4, rb1 = tb1 + q * 4;
#pragma unroll
      for (int rg = 0; rg < 4; rg++) {
        if (rb0 + rg < 63) regS[nt3] += fmaxf(e0[rg] + b3v, 0.f);
        if (rb1 + rg < 63) regS[nt3] += fmaxf(e1[rg] + b3v, 0.f);
      }
    }
  }
  // reduce over the 4 q-lane groups; lane (c,q) writes col q*16+c (coalesced 256B store)
  float t0 = regS[0], t1 = regS[1], t2 = regS[2], t3 = regS[3];
  t0 += __shfl_xor(t0, 16); t0 += __shfl_xor(t0, 32);
  t1 += __shfl_xor(t1, 16); t1 += __shfl_xor(t1, 32);
  t2 += __shfl_xor(t2, 16); t2 += __shfl_xor(t2, 32);
  t3 += __shfl_xor(t3, 16); t3 += __shfl_xor(t3, 32);
  float v = q == 0 ? t0 : (q == 1 ? t1 : (q == 2 ? t2 : t3));
  outp[q * 16 + c] = v;
}

__device__ __forceinline__ void pv_wave(
    const _Float16* __restrict__ Arow, const _Float16* __restrict__ Bb,
    const _Float16* sW2, const _Float16* __restrict__ w2g,
    const _Float16* __restrict__ w3g,
    const float* __restrict__ b2g, const float* __restrict__ b3g,
    _Float16* sH, int lane, float* __restrict__ outp) {
  int c = lane & 15, q = lane >> 4;
  int z0 = 0;
  asm volatile("" : "+v"(z0));
  int v14 = c > 13 ? 13 : c;
  const _Float16* bp = Bb + v14 * HH;
  half8 av[4];
#pragma unroll
  for (int ks = 0; ks < 4; ks++)
    av[ks] = *(const half8*)(Arow + ks * 32 + q * 8);
  floatx4 acc[8];
#pragma unroll
  for (int nt = 0; nt < 8; nt++) acc[nt] = (floatx4){0.f, 0.f, 0.f, 0.f};
#pragma unroll
  for (int ks = 0; ks < 4; ks++) {
    half8 bv = *(const half8*)(bp + ks * 32 + q * 8);
    half8 h = av[ks] + bv;
#pragma unroll
    for (int j = 0; j < 8; j++) h[j] = h[j] > (_Float16)0.f ? h[j] : (_Float16)0.f;
#pragma unroll
    for (int nt = 0; nt < 8; nt++) {
      half8 w;
      if (nt < 4) w = *(const half8*)(&sW2[((nt * 4 + ks) << 9) + (lane << 3)]);
      else        w = *(const half8*)(&w2g[z0 + ((nt * 4 + ks) << 9) + (lane << 3)]);
      acc[nt] = MFMA(w, h, acc[nt]);
    }
  }
#pragma unroll
  for (int nt = 0; nt < 8; nt++) {
    float4 bbt = *(const float4*)(&b2g[z0 + nt * 16 + q * 4]);
    half4v g0;
    g0[0] = (_Float16)fmaxf(acc[nt][0] + bbt.x, 0.f);
    g0[1] = (_Float16)fmaxf(acc[nt][1] + bbt.y, 0.f);
    g0[2] = (_Float16)fmaxf(acc[nt][2] + bbt.z, 0.f);
    g0[3] = (_Float16)fmaxf(acc[nt][3] + bbt.w, 0.f);
    int slot = ((nt << 1) + (q >> 1)) ^ c;
    int addr = (c << 7) + (slot << 3) + ((q & 1) << 2);
    *(half4v*)(&sH[addr]) = g0;
  }
  half8 a2[4];
#pragma unroll
  for (int ks = 0; ks < 4; ks++) {
    int addr = (c << 7) + ((((ks << 2) + q) ^ c) << 3);
    a2[ks] = *(const half8*)(&sH[addr]);
  }
  floatx4 regS = {0.f, 0.f, 0.f, 0.f};
#pragma unroll
  for (int nt3 = 0; nt3 < 4; nt3++) {
    floatx4 e = {0.f, 0.f, 0.f, 0.f};
#pragma unroll
    for (int ks = 0; ks < 4; ks++) {
      half8 wf = *(const half8*)(&w3g[z0 + ((nt3 * 4 + ks) << 9) + (lane << 3)]);
      e = MFMA(a2[ks], wf, e);
    }
    float b3v = b3g[z0 + nt3 * 16 + c];
    int rb = q * 4;
#pragma unroll
    for (int rg = 0; rg < 4; rg++) {
      if (rb + rg < 14) regS[nt3] += fmaxf(e[rg] + b3v, 0.f);
    }
  }
  float t0 = regS[0], t1 = regS[1], t2 = regS[2], t3 = regS[3];
  t0 += __shfl_xor(t0, 16); t0 += __shfl_xor(t0, 32);
  t1 += __shfl_xor(t1, 16); t1 += __shfl_xor(t1, 32);
  t2 += __shfl_xor(t2, 16); t2 += __shfl_xor(t2, 32);
  t3 += __shfl_xor(t3, 16); t3 += __shfl_xor(t3, 32);
  float v = q == 0 ? t0 : (q == 1 ? t1 : (q == 2 ? t2 : t3));
  outp[q * 16 + c] = v;
}

#define PPB4 (NB * 8)              // 1024 pp blocks (8 receivers each)
#define EGRID4 (NB * 8 + NB * 2)   // + 256 pv blocks (32 k-nodes each) = 1280 = 5 x 256 CUs
__global__ __launch_bounds__(256, 4) void edge_fused(
    const _Float16* __restrict__ A1h, const _Float16* __restrict__ B1h,
    const _Float16* __restrict__ A1pvh, const _Float16* __restrict__ B1pvh,
    const float* __restrict__ fr2_b, const float* __restrict__ fr3_b,
    const float* __restrict__ fr2pv_b, const float* __restrict__ fr3pv_b,
    const _Float16* __restrict__ WT,
    float* __restrict__ Epp, float* __restrict__ Epv) {
  __shared__ __align__(16) _Float16 sW2[8192];      // 16 KB: W2 nt 0..3 (frag-major)
  __shared__ __align__(16) _Float16 sH2s[4][2048];  // 16 KB: one private 4KB slice/wave
  // total LDS = 32768 B exactly -> 5 blocks/CU
  int tid = threadIdx.x;
  int lane = tid & 63, wv = tid >> 6;
  bool ispp = blockIdx.x < PPB4;
  const _Float16* w2base = ispp ? (WT + OFF_W2) : (WT + OFF_W2PV);
  for (int i = tid; i < 1024; i += 256)
    *(uint4*)(&sW2[i * 8]) = *(const uint4*)(&w2base[i * 8]);
  const float* b2g = ispp ? fr2_b : fr2pv_b;
  const float* b3g = ispp ? fr3_b : fr3pv_b;
  __syncthreads();   // the ONLY block-wide barrier
  if (ispp) {
    int b = blockIdx.x >> 3, rb = (blockIdx.x & 7) << 3;
#pragma unroll 1
    for (int rcv = 0; rcv < 2; rcv++) {
      int r = rb + wv * 2 + rcv;
      pp_wave(A1h + (b * NN + r) * HH, B1h + b * NN * HH,
              sW2, WT + OFF_W2, WT + OFF_W3, b2g, b3g,
              &sH2s[wv][0], r, lane, Epp + (b * NN + r) * DE);
    }
  } else {
    int p = blockIdx.x - PPB4;
    int b = p >> 1, k0 = (p & 1) << 5;
#pragma unroll 1
    for (int kk = 0; kk < 8; kk++) {
      int k = k0 + wv * 8 + kk;
      pv_wave(A1pvh + (b * NN + k) * HH, B1pvh + b * NV * HH,
              sW2, WT + OFF_W2PV, WT + OFF_W3PV, b2g, b3g,
              &sH2s[wv][0], lane, Epv + (b * NN + k) * DE);
    }
  }
}

// ---------------- NODE: C=[x|Epp|Epv] -> fo1,fo2,fo3 -> pool -> fc ----------------
__global__ __launch_bounds__(256) void node_out(
    const float* __restrict__ x, const float* __restrict__ Epp,
    const float* __restrict__ Epv,
    const float* __restrict__ fo1_b, const float* __restrict__ fo2_b,
    const float* __restrict__ fo3_b,
    const float* __restrict__ fc_w, const float* __restrict__ fc_b,
    const _Float16* __restrict__ WT, float* __restrict__ out) {
  __shared__ _Float16 sC[16 * 168];
  __shared__ _Float16 sHa[16 * PITCH];
  __shared__ _Float16 sHb[16 * PITCH];
  __shared__ float sPool[64];
  int tid = threadIdx.x;
  int b = blockIdx.x >> 2, r0 = (blockIdx.x & 3) << 4;
  for (int i = tid; i < 16 * 32; i += 256) {
    int row = i >> 5, p = i & 31;
    sC[row * 168 + p] = (_Float16)x[b * (PP * NN) + p * 64 + r0 + row];
  }
  for (int i = tid; i < 16 * 16; i += 256) {
    int row = i >> 4, d4 = i & 15;
    float4 vpp = *(const float4*)(&Epp[(b * NN + r0 + row) * DE + d4 * 4]);
    float4 vpv = *(const float4*)(&Epv[(b * NN + r0 + row) * DE + d4 * 4]);
    half4v hpp, hpv;
    hpp[0] = (_Float16)vpp.x; hpp[1] = (_Float16)vpp.y;
    hpp[2] = (_Float16)vpp.z; hpp[3] = (_Float16)vpp.w;
    hpv[0] = (_Float16)vpv.x; hpv[1] = (_Float16)vpv.y;
    hpv[2] = (_Float16)vpv.z; hpv[3] = (_Float16)vpv.w;
    *(half4v*)(&sC[row * 168 + 32 + d4 * 4]) = hpp;
    *(half4v*)(&sC[row * 168 + 96 + d4 * 4]) = hpv;
  }
  __syncthreads();
  int lane = tid & 63, wv = tid >> 6;
  int c = lane & 15, q = lane >> 4;
  // fo1 (K=160), transposed-C; wave owns cols wv*32..+31
  half8 cf[5];
#pragma unroll
  for (int ks = 0; ks < 5; ks++)
    cf[ks] = *(const half8*)(&sC[c * 168 + ks * 32 + q * 8]);
#pragma unroll
  for (int nt2 = 0; nt2 < 2; nt2++) {
    int nt = wv * 2 + nt2;
    floatx4 a0 = {0.f, 0.f, 0.f, 0.f};
#pragma unroll
    for (int ks = 0; ks < 5; ks++) {
      half8 wf = *(const half8*)(&WT[OFF_FO1 + ((nt * 5 + ks) << 9) + (lane << 3)]);
      a0 = MFMA(wf, cf[ks], a0);
    }
    float4 bb = *(const float4*)(&fo1_b[nt * 16 + q * 4]);
    half4v h0;
    h0[0] = (_Float16)fmaxf(a0[0] + bb.x, 0.f);
    h0[1] = (_Float16)fmaxf(a0[1] + bb.y, 0.f);
    h0[2] = (_Float16)fmaxf(a0[2] + bb.z, 0.f);
    h0[3] = (_Float16)fmaxf(a0[3] + bb.w, 0.f);
    *(half4v*)(&sHa[c * PITCH + nt * 16 + q * 4]) = h0;
  }
  __syncthreads();
  // fo2 (K=128), transposed-C
  half8 g1[4];
#pragma unroll
  for (int ks = 0; ks < 4; ks++)
    g1[ks] = *(const half8*)(&sHa[c * PITCH + ks * 32 + q * 8]);
#pragma unroll
  for (int nt2 = 0; nt2 < 2; nt2++) {
    int nt = wv * 2 + nt2;
    floatx4 a0 = {0.f, 0.f, 0.f, 0.f};
#pragma unroll
    for (int ks = 0; ks < 4; ks++) {
      half8 wf = *(const half8*)(&WT[OFF_FO2 + ((nt * 4 + ks) << 9) + (lane << 3)]);
      a0 = MFMA(wf, g1[ks], a0);
    }
    float4 bb = *(const float4*)(&fo2_b[nt * 16 + q * 4]);
    half4v h0;
    h0[0] = (_Float16)fmaxf(a0[0] + bb.x, 0.f);
    h0[1] = (_Float16)fmaxf(a0[1] + bb.y, 0.f);
    h0[2] = (_Float16)fmaxf(a0[2] + bb.z, 0.f);
    h0[3] = (_Float16)fmaxf(a0[3] + bb.w, 0.f);
    *(half4v*)(&sHb[c * PITCH + nt * 16 + q * 4]) = h0;
  }
  __syncthreads();
  // fo3 (N=64): wave owns 16 cols; pool over the 16 real nodes
  half8 g2[4];
#pragma unroll
  for (int ks = 0; ks < 4; ks++)
    g2[ks] = *(const half8*)(&sHb[c * PITCH + ks * 32 + q * 8]);
  floatx4 e0 = {0.f, 0.f, 0.f, 0.f};
#pragma unroll
  for (int ks = 0; ks < 4; ks++) {
    half8 wf = *(const half8*)(&WT[OFF_FO3 + ((wv * 4 + ks) << 9) + (lane << 3)]);
    e0 = MFMA(g2[ks], wf, e0);
  }
  float bb3 = fo3_b[wv * 16 + c];
  float s = 0.f;
#pragma unroll
  for (int rg = 0; rg < 4; rg++) s += fmaxf(e0[rg] + bb3, 0.f);
  s += __shfl_xor(s, 16);
  s += __shfl_xor(s, 32);
  if (lane < 16) sPool[wv * 16 + c] = s;
  __syncthreads();
  if (tid < NCLS) {
    float o = ((blockIdx.x & 3) == 0) ? fc_b[tid] : 0.f;
#pragma unroll
    for (int d = 0; d < 64; d++) o += sPool[d] * fc_w[d * NCLS + tid];
    atomicAdd(&out[b * NCLS + tid], o);
  }
}

extern "C" void kernel_launch(void* const* d_in, const int* in_sizes, int n_in,
                              void* d_out, int out_size, void* d_ws, size_t ws_size,
                              hipStream_t stream) {
  const float* x = (const float*)d_in[0];
  const float* y = (const float*)d_in[1];
  const float* fr1_w = (const float*)d_in[2];  const float* fr1_b = (const float*)d_in[3];
  const float* fr2_w = (const float*)d_in[4];  const float* fr2_b = (const float*)d_in[5];
  const float* fr3_w = (const float*)d_in[6];  const float* fr3_b = (const float*)d_in[7];
  const float* fr1pv_w = (const float*)d_in[8];  const float* fr1pv_b = (const float*)d_in[9];
  const float* fr2pv_w = (const float*)d_in[10]; const float* fr2pv_b = (const float*)d_in[11];
  const float* fr3pv_w = (const float*)d_in[12]; const float* fr3pv_b = (const float*)d_in[13];
  const float* fo1_w = (const float*)d_in[14];  const float* fo1_b = (const float*)d_in[15];
  const float* fo2_w = (const float*)d_in[16];  const float* fo2_b = (const float*)d_in[17];
  const float* fo3_w = (const float*)d_in[18];  const float* fo3_b = (const float*)d_in[19];
  const float* fc_w = (const float*)d_in[20];   const float* fc_b = (const float*)d_in[21];

  char* ws = (char*)d_ws;
  _Float16* A1h   = (_Float16*)(ws);                 // [128][64][128] fp16 (bias folded)
  _Float16* B1h   = (_Float16*)(ws + (2u << 20));
  _Float16* A1pvh = (_Float16*)(ws + (4u << 20));    // (bias folded)
  _Float16* B1pvh = (_Float16*)(ws + (6u << 20));    // [128][14][128] fp16
  _Float16* WT    = (_Float16*)(ws + (7u << 20));    // frag-major fp16 weights (~200 KB)
  float* Epp      = (float*)(ws + (8u << 20));       // [128][64][64] f32
  float* Epv      = (float*)(ws + (10u << 20));      // [128][64][64] f32

  k0_prep<<<926, 256, 0, stream>>>(x, y, fr1_w, fr1_b, fr1pv_w, fr1pv_b,
                                   fr2_w, fr3_w, fr2pv_w, fr3pv_w,
                                   fo1_w, fo2_w, fo3_w,
                                   A1h, B1h, A1pvh, B1pvh, WT, (float*)d_out);
  edge_fused<<<EGRID4, 256, 0, stream>>>(A1h, B1h, A1pvh, B1pvh,
                                         fr2_b, fr3_b, fr2pv_b, fr3pv_b,
                                         WT, Epp, Epv);
  node_out<<<NB * 4, 256, 0, stream>>>(x, Epp, Epv, fo1_b, fo2_b, fo3_b,
                                       fc_w, fc_b, WT, (float*)d_out);
}

// Round 13
// 195.661 us; speedup vs baseline: 1.0915x; 1.0915x over previous
//
#include <hip/hip_runtime.h>

typedef __attribute__((ext_vector_type(8))) _Float16 half8;
typedef __attribute__((ext_vector_type(4))) _Float16 half4v;
typedef __attribute__((ext_vector_type(4))) float floatx4;

#define NB 128
#define NN 64
#define NV 14
#define PP 32
#define SS 14
#define HH 128
#define DE 64
#define NCLS 5
#define PITCH 136   // halves; used by node_out only

// fragment-major weight offsets (halves). layout: [nt][ks][lane][8]
#define OFF_W2   0
#define OFF_W3   16384
#define OFF_W2PV 24576
#define OFF_W3PV 40960
#define OFF_FO1  49152
#define OFF_FO2  69632
#define OFF_FO3  86016

__device__ __forceinline__ floatx4 MFMA(half8 a, half8 b, floatx4 c) {
  return __builtin_amdgcn_mfma_f32_16x16x32_f16(a, b, c, 0, 0, 0);
}

// ---------------- K0: fp16 layer-1 terms (+bias fold), frag-major weights, d_out zero ----------------
__global__ __launch_bounds__(256) void k0_prep(
    const float* __restrict__ x, const float* __restrict__ y,
    const float* __restrict__ fr1_w, const float* __restrict__ fr1_b,
    const float* __restrict__ fr1pv_w, const float* __restrict__ fr1pv_b,
    const float* __restrict__ fr2_w, const float* __restrict__ fr3_w,
    const float* __restrict__ fr2pv_w, const float* __restrict__ fr3pv_w,
    const float* __restrict__ fo1_w, const float* __restrict__ fo2_w,
    const float* __restrict__ fo3_w,
    _Float16* __restrict__ A1h, _Float16* __restrict__ B1h,
    _Float16* __restrict__ A1pvh, _Float16* __restrict__ B1pvh,
    _Float16* __restrict__ WT, float* __restrict__ dout) {
  int blk = blockIdx.x;
  int tid = threadIdx.x;
  if (blk < 768) {
    int mat = blk >> 8, sub = blk & 255;
    int b = sub >> 1, n0 = (sub & 1) << 5;
    __shared__ float sxT[32 * 33];
    for (int i = tid; i < 32 * PP; i += 256) {
      int p = i >> 5, n = i & 31;
      sxT[n * 33 + p] = x[b * (PP * NN) + p * 64 + n0 + n];
    }
    __syncthreads();
    const float* w; _Float16* outp; const float* bias;
    if (mat == 0)      { w = fr1_w;           outp = A1h;   bias = fr1_b; }
    else if (mat == 1) { w = fr1_w + 32 * HH; outp = B1h;   bias = nullptr; }
    else               { w = fr1pv_w;         outp = A1pvh; bias = fr1pv_b; }
    for (int o = tid; o < 32 * 32; o += 256) {
      int n = o >> 5, jc = o & 31;
      float4 acc = {0.f, 0.f, 0.f, 0.f};
      const float* xr = &sxT[n * 33];
#pragma unroll 8
      for (int k = 0; k < PP; k++) {
        float xv = xr[k];
        float4 wv = ((const float4*)w)[k * 32 + jc];
        acc.x += xv * wv.x; acc.y += xv * wv.y;
        acc.z += xv * wv.z; acc.w += xv * wv.w;
      }
      if (bias) {
        float4 bv = ((const float4*)bias)[jc];
        acc.x += bv.x; acc.y += bv.y; acc.z += bv.z; acc.w += bv.w;
      }
      half4v hv;
      hv[0] = (_Float16)acc.x; hv[1] = (_Float16)acc.y;
      hv[2] = (_Float16)acc.z; hv[3] = (_Float16)acc.w;
      *(half4v*)(&outp[(b * NN + n0 + n) * HH + jc * 4]) = hv;
    }
  } else if (blk < 896) {
    int b = blk - 768;
    __shared__ float syT[NV * 15];
    for (int i = tid; i < SS * NV; i += 256) {
      int s = i / NV, v = i - s * NV;
      syT[v * 15 + s] = y[b * (SS * NV) + i];
    }
    __syncthreads();
    const float4* w4 = (const float4*)(fr1pv_w + 32 * HH);
    for (int o = tid; o < NV * 32; o += 256) {
      int v = o >> 5, jc = o & 31;
      float4 acc = {0.f, 0.f, 0.f, 0.f};
#pragma unroll
      for (int s = 0; s < SS; s++) {
        float yv = syT[v * 15 + s];
        float4 wv = w4[s * 32 + jc];
        acc.x += yv * wv.x; acc.y += yv * wv.y;
        acc.z += yv * wv.z; acc.w += yv * wv.w;
      }
      half4v hv;
      hv[0] = (_Float16)acc.x; hv[1] = (_Float16)acc.y;
      hv[2] = (_Float16)acc.z; hv[3] = (_Float16)acc.w;
      *(half4v*)(&B1pvh[(b * NV + v) * HH + jc * 4]) = hv;
    }
  } else if (blk < 925) {
    // frag-major transform, one block per (matrix, ks):
    // dst[((nt*NKS+ks)*64 + l)*8 + j] = src[(ks*32 + qq*8 + j)*N + nt*16 + cc]
    int t = blk - 896;
    int wid, ks;
    if (t < 16)      { wid = t >> 2; ks = t & 3; }
    else if (t < 21) { wid = 4; ks = t - 16; }
    else if (t < 25) { wid = 5; ks = t - 21; }
    else             { wid = 6; ks = t - 25; }
    const float* src; int N, NKS, NTN; _Float16* dst;
    switch (wid) {
      case 0: src = fr2_w;   N = 128; NKS = 4; NTN = 8; dst = WT + OFF_W2;   break;
      case 1: src = fr3_w;   N = 64;  NKS = 4; NTN = 4; dst = WT + OFF_W3;   break;
      case 2: src = fr2pv_w; N = 128; NKS = 4; NTN = 8; dst = WT + OFF_W2PV; break;
      case 3: src = fr3pv_w; N = 64;  NKS = 4; NTN = 4; dst = WT + OFF_W3PV; break;
      case 4: src = fo1_w;   N = 128; NKS = 5; NTN = 8; dst = WT + OFF_FO1;  break;
      case 5: src = fo2_w;   N = 128; NKS = 4; NTN = 8; dst = WT + OFF_FO2;  break;
      default: src = fo3_w;  N = 64;  NKS = 4; NTN = 4; dst = WT + OFF_FO3;  break;
    }
    __shared__ float sw[32 * 132];   // 32 rows x (N<=128, +4 pad) = 16.5 KB
    int NP = N + 4;
    int n4 = N >> 2;
    for (int i = tid; i < 32 * n4; i += 256) {
      int row = i / n4, c4 = i - row * n4;
      *(float4*)(&sw[row * NP + c4 * 4]) = *(const float4*)(&src[(ks * 32 + row) * N + c4 * 4]);
    }
    __syncthreads();
    for (int o = tid; o < NTN * 64; o += 256) {
      int nt = o >> 6, l = o & 63;
      int cc = l & 15, qq = l >> 4;
      half8 hv;
#pragma unroll
      for (int j = 0; j < 8; j++) hv[j] = (_Float16)sw[(qq * 8 + j) * NP + nt * 16 + cc];
      *(half8*)(&dst[((nt * NKS + ks) * 64 + l) << 3]) = hv;
    }
  } else {
    for (int i = tid; i < NB * NCLS; i += 256) dout[i] = 0.f;
  }
}

// ---------------- fused EDGE kernel: receiver-major + uniform 32-tile blocks ----------------
// r12 post-mortem: __launch_bounds__(256,4) capped VGPR at 64 -> 66 MB spill (3rd spill
// event; rule: this body needs >=72 VGPR, never hint below 128). This round: identical
// structure, bounds back to (256,2). VGPR ~72 -> 4 blocks/CU (VGPR bucket), LDS 32 KB
// allows 5 -> VGPR-capped at 4. Uniform blocks (32 tiles each) kill r11's pv-idle-slot.
//   pp: 1024 blocks x 8 receivers (2/wave); pv: 256 blocks x 32 k-nodes (8/wave).
//   LDS = 32768 B: W2 nt0-3 (16 KB) + 4x4KB sH slices; W2 nt4-7 + biases via global
//   (L1-hot, z0-laundered). No barriers after staging, no atomics, reg-resident sums.
__device__ __forceinline__ void pp_wave(
    const _Float16* __restrict__ Arow, const _Float16* __restrict__ Bb,
    const _Float16* sW2, const _Float16* __restrict__ w2g,
    const _Float16* __restrict__ w3g,
    const float* __restrict__ b2g, const float* __restrict__ b3g,
    _Float16* sH, int r, int lane, float* __restrict__ outp) {
  int c = lane & 15, q = lane >> 4;
  half8 av[4];
#pragma unroll
  for (int ks = 0; ks < 4; ks++)
    av[ks] = *(const half8*)(Arow + ks * 32 + q * 8);
  floatx4 regS = {0.f, 0.f, 0.f, 0.f};
#pragma unroll 1
  for (int tp = 0; tp < 2; tp++) {
    int z0 = 0;
    asm volatile("" : "+v"(z0));   // defeats LICM of W2-hi/W3/bias loads across iterations
    int tb0 = tp * 32, tb1 = tb0 + 16;
    int jj0 = tb0 + c; if (jj0 > 62) jj0 = 62;
    int s0 = jj0 + (jj0 >= r ? 1 : 0);
    int jj1 = tb1 + c; if (jj1 > 62) jj1 = 62;
    int s1 = jj1 + (jj1 >= r ? 1 : 0);
    const _Float16* b0p = Bb + s0 * HH;
    const _Float16* b1p = Bb + s1 * HH;
    floatx4 acc0[8], acc1[8];
#pragma unroll
    for (int nt = 0; nt < 8; nt++) {
      acc0[nt] = (floatx4){0.f, 0.f, 0.f, 0.f};
      acc1[nt] = (floatx4){0.f, 0.f, 0.f, 0.f};
    }
#pragma unroll
    for (int ks = 0; ks < 4; ks++) {
      half8 bv0 = *(const half8*)(b0p + ks * 32 + q * 8);
      half8 bv1 = *(const half8*)(b1p + ks * 32 + q * 8);
      half8 h0 = av[ks] + bv0;
      half8 h1 = av[ks] + bv1;
#pragma unroll
      for (int j = 0; j < 8; j++) {
        h0[j] = h0[j] > (_Float16)0.f ? h0[j] : (_Float16)0.f;
        h1[j] = h1[j] > (_Float16)0.f ? h1[j] : (_Float16)0.f;
      }
#pragma unroll
      for (int nt = 0; nt < 8; nt++) {
        half8 w;
        if (nt < 4) w = *(const half8*)(&sW2[((nt * 4 + ks) << 9) + (lane << 3)]);
        else        w = *(const half8*)(&w2g[z0 + ((nt * 4 + ks) << 9) + (lane << 3)]);
        acc0[nt] = MFMA(w, h0, acc0[nt]);
        acc1[nt] = MFMA(w, h1, acc1[nt]);
      }
    }
    // L2 epilogue: tile0 -> sH now, tile1 parks in regs (time-shared slice, r7)
    half4v g1r[8];
#pragma unroll
    for (int nt = 0; nt < 8; nt++) {
      float4 bbt = *(const float4*)(&b2g[z0 + nt * 16 + q * 4]);
      half4v g0, g1;
      g0[0] = (_Float16)fmaxf(acc0[nt][0] + bbt.x, 0.f);
      g0[1] = (_Float16)fmaxf(acc0[nt][1] + bbt.y, 0.f);
      g0[2] = (_Float16)fmaxf(acc0[nt][2] + bbt.z, 0.f);
      g0[3] = (_Float16)fmaxf(acc0[nt][3] + bbt.w, 0.f);
      g1[0] = (_Float16)fmaxf(acc1[nt][0] + bbt.x, 0.f);
      g1[1] = (_Float16)fmaxf(acc1[nt][1] + bbt.y, 0.f);
      g1[2] = (_Float16)fmaxf(acc1[nt][2] + bbt.z, 0.f);
      g1[3] = (_Float16)fmaxf(acc1[nt][3] + bbt.w, 0.f);
      int slot = ((nt << 1) + (q >> 1)) ^ c;
      int addr = (c << 7) + (slot << 3) + ((q & 1) << 2);
      *(half4v*)(&sH[addr]) = g0;
      g1r[nt] = g1;
    }
    half8 a20[4], a21[4];
#pragma unroll
    for (int ks = 0; ks < 4; ks++) {
      int addr = (c << 7) + ((((ks << 2) + q) ^ c) << 3);
      a20[ks] = *(const half8*)(&sH[addr]);
    }
#pragma unroll
    for (int nt = 0; nt < 8; nt++) {
      int slot = ((nt << 1) + (q >> 1)) ^ c;
      int addr = (c << 7) + (slot << 3) + ((q & 1) << 2);
      *(half4v*)(&sH[addr]) = g1r[nt];
    }
#pragma unroll
    for (int ks = 0; ks < 4; ks++) {
      int addr = (c << 7) + ((((ks << 2) + q) ^ c) << 3);
      a21[ks] = *(const half8*)(&sH[addr]);
    }
    // L3: shared W3 loads feed both tiles; masked accumulate into regS
#pragma unroll
    for (int nt3 = 0; nt3 < 4; nt3++) {
      floatx4 e0 = {0.f, 0.f, 0.f, 0.f};
      floatx4 e1 = {0.f, 0.f, 0.f, 0.f};
#pragma unroll
      for (int ks = 0; ks < 4; ks++) {
        half8 wf = *(const half8*)(&w3g[z0 + ((nt3 * 4 + ks) << 9) + (lane << 3)]);
        e0 = MFMA(a20[ks], wf, e0);
        e1 = MFMA(a21[ks], wf, e1);
      }
      float b3v = b3g[z0 + nt3 * 16 + c];
      int rb0 = tb0 + q * 4, rb1 = tb1 + q * 4;
#pragma unroll
      for (int rg = 0; rg < 4; rg++) {
        if (rb0 + rg < 63) regS[nt3] += fmaxf(e0[rg] + b3v, 0.f);
        if (rb1 + rg < 63) regS[nt3] += fmaxf(e1[rg] + b3v, 0.f);
      }
    }
  }
  // reduce over the 4 q-lane groups; lane (c,q) writes col q*16+c (coalesced 256B store)
  float t0 = regS[0], t1 = regS[1], t2 = regS[2], t3 = regS[3];
  t0 += __shfl_xor(t0, 16); t0 += __shfl_xor(t0, 32);
  t1 += __shfl_xor(t1, 16); t1 += __shfl_xor(t1, 32);
  t2 += __shfl_xor(t2, 16); t2 += __shfl_xor(t2, 32);
  t3 += __shfl_xor(t3, 16); t3 += __shfl_xor(t3, 32);
  float v = q == 0 ? t0 : (q == 1 ? t1 : (q == 2 ? t2 : t3));
  outp[q * 16 + c] = v;
}

__device__ __forceinline__ void pv_wave(
    const _Float16* __restrict__ Arow, const _Float16* __restrict__ Bb,
    const _Float16* sW2, const _Float16* __restrict__ w2g,
    const _Float16* __restrict__ w3g,
    const float* __restrict__ b2g, const float* __restrict__ b3g,
    _Float16* sH, int lane, float* __restrict__ outp) {
  int c = lane & 15, q = lane >> 4;
  int z0 = 0;
  asm volatile("" : "+v"(z0));
  int v14 = c > 13 ? 13 : c;
  const _Float16* bp = Bb + v14 * HH;
  half8 av[4];
#pragma unroll
  for (int ks = 0; ks < 4; ks++)
    av[ks] = *(const half8*)(Arow + ks * 32 + q * 8);
  floatx4 acc[8];
#pragma unroll
  for (int nt = 0; nt < 8; nt++) acc[nt] = (floatx4){0.f, 0.f, 0.f, 0.f};
#pragma unroll
  for (int ks = 0; ks < 4; ks++) {
    half8 bv = *(const half8*)(bp + ks * 32 + q * 8);
    half8 h = av[ks] + bv;
#pragma unroll
    for (int j = 0; j < 8; j++) h[j] = h[j] > (_Float16)0.f ? h[j] : (_Float16)0.f;
#pragma unroll
    for (int nt = 0; nt < 8; nt++) {
      half8 w;
      if (nt < 4) w = *(const half8*)(&sW2[((nt * 4 + ks) << 9) + (lane << 3)]);
      else        w = *(const half8*)(&w2g[z0 + ((nt * 4 + ks) << 9) + (lane << 3)]);
      acc[nt] = MFMA(w, h, acc[nt]);
    }
  }
#pragma unroll
  for (int nt = 0; nt < 8; nt++) {
    float4 bbt = *(const float4*)(&b2g[z0 + nt * 16 + q * 4]);
    half4v g0;
    g0[0] = (_Float16)fmaxf(acc[nt][0] + bbt.x, 0.f);
    g0[1] = (_Float16)fmaxf(acc[nt][1] + bbt.y, 0.f);
    g0[2] = (_Float16)fmaxf(acc[nt][2] + bbt.z, 0.f);
    g0[3] = (_Float16)fmaxf(acc[nt][3] + bbt.w, 0.f);
    int slot = ((nt << 1) + (q >> 1)) ^ c;
    int addr = (c << 7) + (slot << 3) + ((q & 1) << 2);
    *(half4v*)(&sH[addr]) = g0;
  }
  half8 a2[4];
#pragma unroll
  for (int ks = 0; ks < 4; ks++) {
    int addr = (c << 7) + ((((ks << 2) + q) ^ c) << 3);
    a2[ks] = *(const half8*)(&sH[addr]);
  }
  floatx4 regS = {0.f, 0.f, 0.f, 0.f};
#pragma unroll
  for (int nt3 = 0; nt3 < 4; nt3++) {
    floatx4 e = {0.f, 0.f, 0.f, 0.f};
#pragma unroll
    for (int ks = 0; ks < 4; ks++) {
      half8 wf = *(const half8*)(&w3g[z0 + ((nt3 * 4 + ks) << 9) + (lane << 3)]);
      e = MFMA(a2[ks], wf, e);
    }
    float b3v = b3g[z0 + nt3 * 16 + c];
    int rb = q * 4;
#pragma unroll
    for (int rg = 0; rg < 4; rg++) {
      if (rb + rg < 14) regS[nt3] += fmaxf(e[rg] + b3v, 0.f);
    }
  }
  float t0 = regS[0], t1 = regS[1], t2 = regS[2], t3 = regS[3];
  t0 += __shfl_xor(t0, 16); t0 += __shfl_xor(t0, 32);
  t1 += __shfl_xor(t1, 16); t1 += __shfl_xor(t1, 32);
  t2 += __shfl_xor(t2, 16); t2 += __shfl_xor(t2, 32);
  t3 += __shfl_xor(t3, 16); t3 += __shfl_xor(t3, 32);
  float v = q == 0 ? t0 : (q == 1 ? t1 : (q == 2 ? t2 : t3));
  outp[q * 16 + c] = v;
}

#define PPB4 (NB * 8)              // 1024 pp blocks (8 receivers each)
#define EGRID4 (NB * 8 + NB * 2)   // + 256 pv blocks (32 k-nodes each) = 1280 uniform blocks
__global__ __launch_bounds__(256, 2) void edge_fused(
    const _Float16* __restrict__ A1h, const _Float16* __restrict__ B1h,
    const _Float16* __restrict__ A1pvh, const _Float16* __restrict__ B1pvh,
    const float* __restrict__ fr2_b, const float* __restrict__ fr3_b,
    const float* __restrict__ fr2pv_b, const float* __restrict__ fr3pv_b,
    const _Float16* __restrict__ WT,
    float* __restrict__ Epp, float* __restrict__ Epv) {
  __shared__ __align__(16) _Float16 sW2[8192];      // 16 KB: W2 nt 0..3 (frag-major)
  __shared__ __align__(16) _Float16 sH2s[4][2048];  // 16 KB: one private 4KB slice/wave
  // total LDS = 32768 B; residency cap is VGPR bucket (~72 regs -> 4 blocks/CU)
  int tid = threadIdx.x;
  int lane = tid & 63, wv = tid >> 6;
  bool ispp = blockIdx.x < PPB4;
  const _Float16* w2base = ispp ? (WT + OFF_W2) : (WT + OFF_W2PV);
  for (int i = tid; i < 1024; i += 256)
    *(uint4*)(&sW2[i * 8]) = *(const uint4*)(&w2base[i * 8]);
  const float* b2g = ispp ? fr2_b : fr2pv_b;
  const float* b3g = ispp ? fr3_b : fr3pv_b;
  __syncthreads();   // the ONLY block-wide barrier
  if (ispp) {
    int b = blockIdx.x >> 3, rb = (blockIdx.x & 7) << 3;
#pragma unroll 1
    for (int rcv = 0; rcv < 2; rcv++) {
      int r = rb + wv * 2 + rcv;
      pp_wave(A1h + (b * NN + r) * HH, B1h + b * NN * HH,
              sW2, WT + OFF_W2, WT + OFF_W3, b2g, b3g,
              &sH2s[wv][0], r, lane, Epp + (b * NN + r) * DE);
    }
  } else {
    int p = blockIdx.x - PPB4;
    int b = p >> 1, k0 = (p & 1) << 5;
#pragma unroll 1
    for (int kk = 0; kk < 8; kk++) {
      int k = k0 + wv * 8 + kk;
      pv_wave(A1pvh + (b * NN + k) * HH, B1pvh + b * NV * HH,
              sW2, WT + OFF_W2PV, WT + OFF_W3PV, b2g, b3g,
              &sH2s[wv][0], lane, Epv + (b * NN + k) * DE);
    }
  }
}

// ---------------- NODE: C=[x|Epp|Epv] -> fo1,fo2,fo3 -> pool -> fc ----------------
__global__ __launch_bounds__(256) void node_out(
    const float* __restrict__ x, const float* __restrict__ Epp,
    const float* __restrict__ Epv,
    const float* __restrict__ fo1_b, const float* __restrict__ fo2_b,
    const float* __restrict__ fo3_b,
    const float* __restrict__ fc_w, const float* __restrict__ fc_b,
    const _Float16* __restrict__ WT, float* __restrict__ out) {
  __shared__ _Float16 sC[16 * 168];
  __shared__ _Float16 sHa[16 * PITCH];
  __shared__ _Float16 sHb[16 * PITCH];
  __shared__ float sPool[64];
  int tid = threadIdx.x;
  int b = blockIdx.x >> 2, r0 = (blockIdx.x & 3) << 4;
  for (int i = tid; i < 16 * 32; i += 256) {
    int row = i >> 5, p = i & 31;
    sC[row * 168 + p] = (_Float16)x[b * (PP * NN) + p * 64 + r0 + row];
  }
  for (int i = tid; i < 16 * 16; i += 256) {
    int row = i >> 4, d4 = i & 15;
    float4 vpp = *(const float4*)(&Epp[(b * NN + r0 + row) * DE + d4 * 4]);
    float4 vpv = *(const float4*)(&Epv[(b * NN + r0 + row) * DE + d4 * 4]);
    half4v hpp, hpv;
    hpp[0] = (_Float16)vpp.x; hpp[1] = (_Float16)vpp.y;
    hpp[2] = (_Float16)vpp.z; hpp[3] = (_Float16)vpp.w;
    hpv[0] = (_Float16)vpv.x; hpv[1] = (_Float16)vpv.y;
    hpv[2] = (_Float16)vpv.z; hpv[3] = (_Float16)vpv.w;
    *(half4v*)(&sC[row * 168 + 32 + d4 * 4]) = hpp;
    *(half4v*)(&sC[row * 168 + 96 + d4 * 4]) = hpv;
  }
  __syncthreads();
  int lane = tid & 63, wv = tid >> 6;
  int c = lane & 15, q = lane >> 4;
  // fo1 (K=160), transposed-C; wave owns cols wv*32..+31
  half8 cf[5];
#pragma unroll
  for (int ks = 0; ks < 5; ks++)
    cf[ks] = *(const half8*)(&sC[c * 168 + ks * 32 + q * 8]);
#pragma unroll
  for (int nt2 = 0; nt2 < 2; nt2++) {
    int nt = wv * 2 + nt2;
    floatx4 a0 = {0.f, 0.f, 0.f, 0.f};
#pragma unroll
    for (int ks = 0; ks < 5; ks++) {
      half8 wf = *(const half8*)(&WT[OFF_FO1 + ((nt * 5 + ks) << 9) + (lane << 3)]);
      a0 = MFMA(wf, cf[ks], a0);
    }
    float4 bb = *(const float4*)(&fo1_b[nt * 16 + q * 4]);
    half4v h0;
    h0[0] = (_Float16)fmaxf(a0[0] + bb.x, 0.f);
    h0[1] = (_Float16)fmaxf(a0[1] + bb.y, 0.f);
    h0[2] = (_Float16)fmaxf(a0[2] + bb.z, 0.f);
    h0[3] = (_Float16)fmaxf(a0[3] + bb.w, 0.f);
    *(half4v*)(&sHa[c * PITCH + nt * 16 + q * 4]) = h0;
  }
  __syncthreads();
  // fo2 (K=128), transposed-C
  half8 g1[4];
#pragma unroll
  for (int ks = 0; ks < 4; ks++)
    g1[ks] = *(const half8*)(&sHa[c * PITCH + ks * 32 + q * 8]);
#pragma unroll
  for (int nt2 = 0; nt2 < 2; nt2++) {
    int nt = wv * 2 + nt2;
    floatx4 a0 = {0.f, 0.f, 0.f, 0.f};
#pragma unroll
    for (int ks = 0; ks < 4; ks++) {
      half8 wf = *(const half8*)(&WT[OFF_FO2 + ((nt * 4 + ks) << 9) + (lane << 3)]);
      a0 = MFMA(wf, g1[ks], a0);
    }
    float4 bb = *(const float4*)(&fo2_b[nt * 16 + q * 4]);
    half4v h0;
    h0[0] = (_Float16)fmaxf(a0[0] + bb.x, 0.f);
    h0[1] = (_Float16)fmaxf(a0[1] + bb.y, 0.f);
    h0[2] = (_Float16)fmaxf(a0[2] + bb.z, 0.f);
    h0[3] = (_Float16)fmaxf(a0[3] + bb.w, 0.f);
    *(half4v*)(&sHb[c * PITCH + nt * 16 + q * 4]) = h0;
  }
  __syncthreads();
  // fo3 (N=64): wave owns 16 cols; pool over the 16 real nodes
  half8 g2[4];
#pragma unroll
  for (int ks = 0; ks < 4; ks++)
    g2[ks] = *(const half8*)(&sHb[c * PITCH + ks * 32 + q * 8]);
  floatx4 e0 = {0.f, 0.f, 0.f, 0.f};
#pragma unroll
  for (int ks = 0; ks < 4; ks++) {
    half8 wf = *(const half8*)(&WT[OFF_FO3 + ((wv * 4 + ks) << 9) + (lane << 3)]);
    e0 = MFMA(g2[ks], wf, e0);
  }
  float bb3 = fo3_b[wv * 16 + c];
  float s = 0.f;
#pragma unroll
  for (int rg = 0; rg < 4; rg++) s += fmaxf(e0[rg] + bb3, 0.f);
  s += __shfl_xor(s, 16);
  s += __shfl_xor(s, 32);
  if (lane < 16) sPool[wv * 16 + c] = s;
  __syncthreads();
  if (tid < NCLS) {
    float o = ((blockIdx.x & 3) == 0) ? fc_b[tid] : 0.f;
#pragma unroll
    for (int d = 0; d < 64; d++) o += sPool[d] * fc_w[d * NCLS + tid];
    atomicAdd(&out[b * NCLS + tid], o);
  }
}

extern "C" void kernel_launch(void* const* d_in, const int* in_sizes, int n_in,
                              void* d_out, int out_size, void* d_ws, size_t ws_size,
                              hipStream_t stream) {
  const float* x = (const float*)d_in[0];
  const float* y = (const float*)d_in[1];
  const float* fr1_w = (const float*)d_in[2];  const float* fr1_b = (const float*)d_in[3];
  const float* fr2_w = (const float*)d_in[4];  const float* fr2_b = (const float*)d_in[5];
  const float* fr3_w = (const float*)d_in[6];  const float* fr3_b = (const float*)d_in[7];
  const float* fr1pv_w = (const float*)d_in[8];  const float* fr1pv_b = (const float*)d_in[9];
  const float* fr2pv_w = (const float*)d_in[10]; const float* fr2pv_b = (const float*)d_in[11];
  const float* fr3pv_w = (const float*)d_in[12]; const float* fr3pv_b = (const float*)d_in[13];
  const float* fo1_w = (const float*)d_in[14];  const float* fo1_b = (const float*)d_in[15];
  const float* fo2_w = (const float*)d_in[16];  const float* fo2_b = (const float*)d_in[17];
  const float* fo3_w = (const float*)d_in[18];  const float* fo3_b = (const float*)d_in[19];
  const float* fc_w = (const float*)d_in[20];   const float* fc_b = (const float*)d_in[21];

  char* ws = (char*)d_ws;
  _Float16* A1h   = (_Float16*)(ws);                 // [128][64][128] fp16 (bias folded)
  _Float16* B1h   = (_Float16*)(ws + (2u << 20));
  _Float16* A1pvh = (_Float16*)(ws + (4u << 20));    // (bias folded)
  _Float16* B1pvh = (_Float16*)(ws + (6u << 20));    // [128][14][128] fp16
  _Float16* WT    = (_Float16*)(ws + (7u << 20));    // frag-major fp16 weights (~200 KB)
  float* Epp      = (float*)(ws + (8u << 20));       // [128][64][64] f32
  float* Epv      = (float*)(ws + (10u << 20));      // [128][64][64] f32

  k0_prep<<<926, 256, 0, stream>>>(x, y, fr1_w, fr1_b, fr1pv_w, fr1pv_b,
                                   fr2_w, fr3_w, fr2pv_w, fr3pv_w,
                                   fo1_w, fo2_w, fo3_w,
                                   A1h, B1h, A1pvh, B1pvh, WT, (float*)d_out);
  edge_fused<<<EGRID4, 256, 0, stream>>>(A1h, B1h, A1pvh, B1pvh,
                                         fr2_b, fr3_b, fr2pv_b, fr3pv_b,
                                         WT, Epp, Epv);
  node_out<<<NB * 4, 256, 0, stream>>>(x, Epp, Epv, fo1_b, fo2_b, fo3_b,
                                       fc_w, fc_b, WT, (float*)d_out);
}

// Round 14
// 164.682 us; speedup vs baseline: 1.2968x; 1.1881x over previous
//
#include <hip/hip_runtime.h>

typedef __attribute__((ext_vector_type(8))) _Float16 half8;
typedef __attribute__((ext_vector_type(4))) _Float16 half4v;
typedef __attribute__((ext_vector_type(4))) float floatx4;

#define NB 128
#define NN 64
#define NV 14
#define PP 32
#define SS 14
#define HH 128
#define DE 64
#define NCLS 5
#define PITCH 136   // halves; used by node_out only

// fragment-major weight offsets (halves). layout: [nt][ks][lane][8]
#define OFF_W2   0
#define OFF_W3   16384
#define OFF_W2PV 24576
#define OFF_W3PV 40960
#define OFF_FO1  49152
#define OFF_FO2  69632
#define OFF_FO3  86016

__device__ __forceinline__ floatx4 MFMA(half8 a, half8 b, floatx4 c) {
  return __builtin_amdgcn_mfma_f32_16x16x32_f16(a, b, c, 0, 0, 0);
}

// ---------------- K0: fp16 layer-1 terms (+bias fold), frag-major weights, d_out zero ----------------
__global__ __launch_bounds__(256) void k0_prep(
    const float* __restrict__ x, const float* __restrict__ y,
    const float* __restrict__ fr1_w, const float* __restrict__ fr1_b,
    const float* __restrict__ fr1pv_w, const float* __restrict__ fr1pv_b,
    const float* __restrict__ fr2_w, const float* __restrict__ fr3_w,
    const float* __restrict__ fr2pv_w, const float* __restrict__ fr3pv_w,
    const float* __restrict__ fo1_w, const float* __restrict__ fo2_w,
    const float* __restrict__ fo3_w,
    _Float16* __restrict__ A1h, _Float16* __restrict__ B1h,
    _Float16* __restrict__ A1pvh, _Float16* __restrict__ B1pvh,
    _Float16* __restrict__ WT, float* __restrict__ dout) {
  int blk = blockIdx.x;
  int tid = threadIdx.x;
  if (blk < 768) {
    int mat = blk >> 8, sub = blk & 255;
    int b = sub >> 1, n0 = (sub & 1) << 5;
    __shared__ float sxT[32 * 33];
    for (int i = tid; i < 32 * PP; i += 256) {
      int p = i >> 5, n = i & 31;
      sxT[n * 33 + p] = x[b * (PP * NN) + p * 64 + n0 + n];
    }
    __syncthreads();
    const float* w; _Float16* outp; const float* bias;
    if (mat == 0)      { w = fr1_w;           outp = A1h;   bias = fr1_b; }
    else if (mat == 1) { w = fr1_w + 32 * HH; outp = B1h;   bias = nullptr; }
    else               { w = fr1pv_w;         outp = A1pvh; bias = fr1pv_b; }
    for (int o = tid; o < 32 * 32; o += 256) {
      int n = o >> 5, jc = o & 31;
      float4 acc = {0.f, 0.f, 0.f, 0.f};
      const float* xr = &sxT[n * 33];
#pragma unroll 8
      for (int k = 0; k < PP; k++) {
        float xv = xr[k];
        float4 wv = ((const float4*)w)[k * 32 + jc];
        acc.x += xv * wv.x; acc.y += xv * wv.y;
        acc.z += xv * wv.z; acc.w += xv * wv.w;
      }
      if (bias) {
        float4 bv = ((const float4*)bias)[jc];
        acc.x += bv.x; acc.y += bv.y; acc.z += bv.z; acc.w += bv.w;
      }
      half4v hv;
      hv[0] = (_Float16)acc.x; hv[1] = (_Float16)acc.y;
      hv[2] = (_Float16)acc.z; hv[3] = (_Float16)acc.w;
      *(half4v*)(&outp[(b * NN + n0 + n) * HH + jc * 4]) = hv;
    }
  } else if (blk < 896) {
    int b = blk - 768;
    __shared__ float syT[NV * 15];
    for (int i = tid; i < SS * NV; i += 256) {
      int s = i / NV, v = i - s * NV;
      syT[v * 15 + s] = y[b * (SS * NV) + i];
    }
    __syncthreads();
    const float4* w4 = (const float4*)(fr1pv_w + 32 * HH);
    for (int o = tid; o < NV * 32; o += 256) {
      int v = o >> 5, jc = o & 31;
      float4 acc = {0.f, 0.f, 0.f, 0.f};
#pragma unroll
      for (int s = 0; s < SS; s++) {
        float yv = syT[v * 15 + s];
        float4 wv = w4[s * 32 + jc];
        acc.x += yv * wv.x; acc.y += yv * wv.y;
        acc.z += yv * wv.z; acc.w += yv * wv.w;
      }
      half4v hv;
      hv[0] = (_Float16)acc.x; hv[1] = (_Float16)acc.y;
      hv[2] = (_Float16)acc.z; hv[3] = (_Float16)acc.w;
      *(half4v*)(&B1pvh[(b * NV + v) * HH + jc * 4]) = hv;
    }
  } else if (blk < 925) {
    // frag-major transform, one block per (matrix, ks):
    // dst[((nt*NKS+ks)*64 + l)*8 + j] = src[(ks*32 + qq*8 + j)*N + nt*16 + cc]
    int t = blk - 896;
    int wid, ks;
    if (t < 16)      { wid = t >> 2; ks = t & 3; }
    else if (t < 21) { wid = 4; ks = t - 16; }
    else if (t < 25) { wid = 5; ks = t - 21; }
    else             { wid = 6; ks = t - 25; }
    const float* src; int N, NKS, NTN; _Float16* dst;
    switch (wid) {
      case 0: src = fr2_w;   N = 128; NKS = 4; NTN = 8; dst = WT + OFF_W2;   break;
      case 1: src = fr3_w;   N = 64;  NKS = 4; NTN = 4; dst = WT + OFF_W3;   break;
      case 2: src = fr2pv_w; N = 128; NKS = 4; NTN = 8; dst = WT + OFF_W2PV; break;
      case 3: src = fr3pv_w; N = 64;  NKS = 4; NTN = 4; dst = WT + OFF_W3PV; break;
      case 4: src = fo1_w;   N = 128; NKS = 5; NTN = 8; dst = WT + OFF_FO1;  break;
      case 5: src = fo2_w;   N = 128; NKS = 4; NTN = 8; dst = WT + OFF_FO2;  break;
      default: src = fo3_w;  N = 64;  NKS = 4; NTN = 4; dst = WT + OFF_FO3;  break;
    }
    __shared__ float sw[32 * 132];   // 32 rows x (N<=128, +4 pad) = 16.5 KB
    int NP = N + 4;
    int n4 = N >> 2;
    for (int i = tid; i < 32 * n4; i += 256) {
      int row = i / n4, c4 = i - row * n4;
      *(float4*)(&sw[row * NP + c4 * 4]) = *(const float4*)(&src[(ks * 32 + row) * N + c4 * 4]);
    }
    __syncthreads();
    for (int o = tid; o < NTN * 64; o += 256) {
      int nt = o >> 6, l = o & 63;
      int cc = l & 15, qq = l >> 4;
      half8 hv;
#pragma unroll
      for (int j = 0; j < 8; j++) hv[j] = (_Float16)sw[(qq * 8 + j) * NP + nt * 16 + cc];
      *(half8*)(&dst[((nt * NKS + ks) * 64 + l) << 3]) = hv;
    }
  } else {
    for (int i = tid; i < NB * NCLS; i += 256) dout[i] = 0.f;
  }
}

// ---------------- fused EDGE kernel: RECEIVER-MAJOR, barrier-free, atomic-free (r11) ----------------
// Session-best structure, restored verbatim after r12 (spill from bounds hint) and r13
// (W2-split + global biases regression) both lost to it. Each WAVE owns whole receivers;
// receiver sum lives in 4 regs/lane, reduced via 2 shfl_xor, one coalesced 256B store.
// No sEb, no atomics, 1 barrier per block. Full W2 (32 KB) + biases in LDS. W3 via
// z0-laundered global loads (L1-hot). VGPR ~72, LDS 50176 -> 3 blocks/CU.
__device__ __forceinline__ void pp_wave(
    const _Float16* __restrict__ Arow, const _Float16* __restrict__ Bb,
    const _Float16* sW2, const _Float16* __restrict__ w3g,
    const float* sB2, const float* sB3,
    _Float16* sH, int r, int lane, float* __restrict__ outp) {
  int c = lane & 15, q = lane >> 4;
  half8 av[4];
#pragma unroll
  for (int ks = 0; ks < 4; ks++)
    av[ks] = *(const half8*)(Arow + ks * 32 + q * 8);
  floatx4 regS = {0.f, 0.f, 0.f, 0.f};
#pragma unroll 1
  for (int tp = 0; tp < 2; tp++) {
    int z0 = 0;
    asm volatile("" : "+v"(z0));   // defeats LICM of W2/W3/bias loads across iterations
    int tb0 = tp * 32, tb1 = tb0 + 16;
    int jj0 = tb0 + c; if (jj0 > 62) jj0 = 62;
    int s0 = jj0 + (jj0 >= r ? 1 : 0);
    int jj1 = tb1 + c; if (jj1 > 62) jj1 = 62;
    int s1 = jj1 + (jj1 >= r ? 1 : 0);
    const _Float16* b0p = Bb + s0 * HH;
    const _Float16* b1p = Bb + s1 * HH;
    floatx4 acc0[8], acc1[8];
#pragma unroll
    for (int nt = 0; nt < 8; nt++) {
      acc0[nt] = (floatx4){0.f, 0.f, 0.f, 0.f};
      acc1[nt] = (floatx4){0.f, 0.f, 0.f, 0.f};
    }
#pragma unroll
    for (int ks = 0; ks < 4; ks++) {
      half8 bv0 = *(const half8*)(b0p + ks * 32 + q * 8);
      half8 bv1 = *(const half8*)(b1p + ks * 32 + q * 8);
      half8 h0 = av[ks] + bv0;
      half8 h1 = av[ks] + bv1;
#pragma unroll
      for (int j = 0; j < 8; j++) {
        h0[j] = h0[j] > (_Float16)0.f ? h0[j] : (_Float16)0.f;
        h1[j] = h1[j] > (_Float16)0.f ? h1[j] : (_Float16)0.f;
      }
#pragma unroll
      for (int nt = 0; nt < 8; nt++) {
        half8 w = *(const half8*)(&sW2[z0 + ((nt * 4 + ks) << 9) + (lane << 3)]);
        acc0[nt] = MFMA(w, h0, acc0[nt]);
        acc1[nt] = MFMA(w, h1, acc1[nt]);
      }
    }
    // L2 epilogue: tile0 -> sH now, tile1 parks in regs (time-shared slice, r7)
    half4v g1r[8];
#pragma unroll
    for (int nt = 0; nt < 8; nt++) {
      float4 bbt = *(const float4*)(&sB2[z0 + nt * 16 + q * 4]);
      half4v g0, g1;
      g0[0] = (_Float16)fmaxf(acc0[nt][0] + bbt.x, 0.f);
      g0[1] = (_Float16)fmaxf(acc0[nt][1] + bbt.y, 0.f);
      g0[2] = (_Float16)fmaxf(acc0[nt][2] + bbt.z, 0.f);
      g0[3] = (_Float16)fmaxf(acc0[nt][3] + bbt.w, 0.f);
      g1[0] = (_Float16)fmaxf(acc1[nt][0] + bbt.x, 0.f);
      g1[1] = (_Float16)fmaxf(acc1[nt][1] + bbt.y, 0.f);
      g1[2] = (_Float16)fmaxf(acc1[nt][2] + bbt.z, 0.f);
      g1[3] = (_Float16)fmaxf(acc1[nt][3] + bbt.w, 0.f);
      int slot = ((nt << 1) + (q >> 1)) ^ c;
      int addr = (c << 7) + (slot << 3) + ((q & 1) << 2);
      *(half4v*)(&sH[addr]) = g0;
      g1r[nt] = g1;
    }
    half8 a20[4], a21[4];
#pragma unroll
    for (int ks = 0; ks < 4; ks++) {
      int addr = (c << 7) + ((((ks << 2) + q) ^ c) << 3);
      a20[ks] = *(const half8*)(&sH[addr]);
    }
#pragma unroll
    for (int nt = 0; nt < 8; nt++) {
      int slot = ((nt << 1) + (q >> 1)) ^ c;
      int addr = (c << 7) + (slot << 3) + ((q & 1) << 2);
      *(half4v*)(&sH[addr]) = g1r[nt];
    }
#pragma unroll
    for (int ks = 0; ks < 4; ks++) {
      int addr = (c << 7) + ((((ks << 2) + q) ^ c) << 3);
      a21[ks] = *(const half8*)(&sH[addr]);
    }
    // L3: shared W3 loads feed both tiles; masked accumulate into regS
#pragma unroll
    for (int nt3 = 0; nt3 < 4; nt3++) {
      floatx4 e0 = {0.f, 0.f, 0.f, 0.f};
      floatx4 e1 = {0.f, 0.f, 0.f, 0.f};
#pragma unroll
      for (int ks = 0; ks < 4; ks++) {
        half8 wf = *(const half8*)(&w3g[z0 + ((nt3 * 4 + ks) << 9) + (lane << 3)]);
        e0 = MFMA(a20[ks], wf, e0);
        e1 = MFMA(a21[ks], wf, e1);
      }
      float b3v = sB3[z0 + nt3 * 16 + c];
      int rb0 = tb0 + q * 4, rb1 = tb1 + q * 4;
#pragma unroll
      for (int rg = 0; rg < 4; rg++) {
        if (rb0 + rg < 63) regS[nt3] += fmaxf(e0[rg] + b3v, 0.f);
        if (rb1 + rg < 63) regS[nt3] += fmaxf(e1[rg] + b3v, 0.f);
      }
    }
  }
  // reduce over the 4 q-lane groups; lane (c,q) writes col q*16+c (coalesced 256B store)
  float t0 = regS[0], t1 = regS[1], t2 = regS[2], t3 = regS[3];
  t0 += __shfl_xor(t0, 16); t0 += __shfl_xor(t0, 32);
  t1 += __shfl_xor(t1, 16); t1 += __shfl_xor(t1, 32);
  t2 += __shfl_xor(t2, 16); t2 += __shfl_xor(t2, 32);
  t3 += __shfl_xor(t3, 16); t3 += __shfl_xor(t3, 32);
  float v = q == 0 ? t0 : (q == 1 ? t1 : (q == 2 ? t2 : t3));
  outp[q * 16 + c] = v;
}

__device__ __forceinline__ void pv_wave(
    const _Float16* __restrict__ Arow, const _Float16* __restrict__ Bb,
    const _Float16* sW2, const _Float16* __restrict__ w3g,
    const float* sB2, const float* sB3,
    _Float16* sH, int lane, float* __restrict__ outp) {
  int c = lane & 15, q = lane >> 4;
  int z0 = 0;
  asm volatile("" : "+v"(z0));
  int v14 = c > 13 ? 13 : c;
  const _Float16* bp = Bb + v14 * HH;
  half8 av[4];
#pragma unroll
  for (int ks = 0; ks < 4; ks++)
    av[ks] = *(const half8*)(Arow + ks * 32 + q * 8);
  floatx4 acc[8];
#pragma unroll
  for (int nt = 0; nt < 8; nt++) acc[nt] = (floatx4){0.f, 0.f, 0.f, 0.f};
#pragma unroll
  for (int ks = 0; ks < 4; ks++) {
    half8 bv = *(const half8*)(bp + ks * 32 + q * 8);
    half8 h = av[ks] + bv;
#pragma unroll
    for (int j = 0; j < 8; j++) h[j] = h[j] > (_Float16)0.f ? h[j] : (_Float16)0.f;
#pragma unroll
    for (int nt = 0; nt < 8; nt++) {
      half8 w = *(const half8*)(&sW2[z0 + ((nt * 4 + ks) << 9) + (lane << 3)]);
      acc[nt] = MFMA(w, h, acc[nt]);
    }
  }
#pragma unroll
  for (int nt = 0; nt < 8; nt++) {
    float4 bbt = *(const float4*)(&sB2[z0 + nt * 16 + q * 4]);
    half4v g0;
    g0[0] = (_Float16)fmaxf(acc[nt][0] + bbt.x, 0.f);
    g0[1] = (_Float16)fmaxf(acc[nt][1] + bbt.y, 0.f);
    g0[2] = (_Float16)fmaxf(acc[nt][2] + bbt.z, 0.f);
    g0[3] = (_Float16)fmaxf(acc[nt][3] + bbt.w, 0.f);
    int slot = ((nt << 1) + (q >> 1)) ^ c;
    int addr = (c << 7) + (slot << 3) + ((q & 1) << 2);
    *(half4v*)(&sH[addr]) = g0;
  }
  half8 a2[4];
#pragma unroll
  for (int ks = 0; ks < 4; ks++) {
    int addr = (c << 7) + ((((ks << 2) + q) ^ c) << 3);
    a2[ks] = *(const half8*)(&sH[addr]);
  }
  floatx4 regS = {0.f, 0.f, 0.f, 0.f};
#pragma unroll
  for (int nt3 = 0; nt3 < 4; nt3++) {
    floatx4 e = {0.f, 0.f, 0.f, 0.f};
#pragma unroll
    for (int ks = 0; ks < 4; ks++) {
      half8 wf = *(const half8*)(&w3g[z0 + ((nt3 * 4 + ks) << 9) + (lane << 3)]);
      e = MFMA(a2[ks], wf, e);
    }
    float b3v = sB3[z0 + nt3 * 16 + c];
    int rb = q * 4;
#pragma unroll
    for (int rg = 0; rg < 4; rg++) {
      if (rb + rg < 14) regS[nt3] += fmaxf(e[rg] + b3v, 0.f);
    }
  }
  float t0 = regS[0], t1 = regS[1], t2 = regS[2], t3 = regS[3];
  t0 += __shfl_xor(t0, 16); t0 += __shfl_xor(t0, 32);
  t1 += __shfl_xor(t1, 16); t1 += __shfl_xor(t1, 32);
  t2 += __shfl_xor(t2, 16); t2 += __shfl_xor(t2, 32);
  t3 += __shfl_xor(t3, 16); t3 += __shfl_xor(t3, 32);
  float v = q == 0 ? t0 : (q == 1 ? t1 : (q == 2 ? t2 : t3));
  outp[q * 16 + c] = v;
}

#define PPB3 (NB * 4)
#define EGRID3 (NB * 4 + NB * 2)
__global__ __launch_bounds__(256, 2) void edge_fused(
    const _Float16* __restrict__ A1h, const _Float16* __restrict__ B1h,
    const _Float16* __restrict__ A1pvh, const _Float16* __restrict__ B1pvh,
    const float* __restrict__ fr2_b, const float* __restrict__ fr3_b,
    const float* __restrict__ fr2pv_b, const float* __restrict__ fr3pv_b,
    const _Float16* __restrict__ WT,
    float* __restrict__ Epp, float* __restrict__ Epv) {
  __shared__ __align__(16) _Float16 sW2[16384];     // 32 KB block-shared W2 (frag-major)
  __shared__ __align__(16) _Float16 sH2s[4][2048];  // 16 KB: one private 4KB slice/wave
  __shared__ __align__(16) float sB2[128];          // 512 B
  __shared__ __align__(16) float sB3[64];           // 256 B   total ~49.9 KB -> 3 blocks/CU
  int tid = threadIdx.x;
  int lane = tid & 63, wv = tid >> 6;
  bool ispp = blockIdx.x < PPB3;
  const _Float16* w2src = ispp ? (WT + OFF_W2) : (WT + OFF_W2PV);
  for (int i = tid; i < 2048; i += 256)
    *(uint4*)(&sW2[i * 8]) = *(const uint4*)(&w2src[i * 8]);
  const float* b2g = ispp ? fr2_b : fr2pv_b;
  const float* b3g = ispp ? fr3_b : fr3pv_b;
  if (tid < 128) sB2[tid] = b2g[tid];
  else if (tid < 192) sB3[tid - 128] = b3g[tid - 128];
  __syncthreads();   // the ONLY block-wide barrier
  if (ispp) {
    int b = blockIdx.x >> 2, r0 = (blockIdx.x & 3) << 4;
#pragma unroll 1
    for (int rcv = 0; rcv < 4; rcv++) {
      int r = r0 + wv * 4 + rcv;
      pp_wave(A1h + (b * NN + r) * HH, B1h + b * NN * HH,
              sW2, WT + OFF_W3, sB2, sB3,
              &sH2s[wv][0], r, lane, Epp + (b * NN + r) * DE);
    }
  } else {
    int p = blockIdx.x - PPB3;
    int b = p >> 1, hf2 = p & 1;
#pragma unroll 1
    for (int kk = 0; kk < 8; kk++) {
      int k = hf2 * 32 + wv * 8 + kk;
      pv_wave(A1pvh + (b * NN + k) * HH, B1pvh + b * NV * HH,
              sW2, WT + OFF_W3PV, sB2, sB3,
              &sH2s[wv][0], lane, Epv + (b * NN + k) * DE);
    }
  }
}

// ---------------- NODE: C=[x|Epp|Epv] -> fo1,fo2,fo3 -> pool -> fc ----------------
__global__ __launch_bounds__(256) void node_out(
    const float* __restrict__ x, const float* __restrict__ Epp,
    const float* __restrict__ Epv,
    const float* __restrict__ fo1_b, const float* __restrict__ fo2_b,
    const float* __restrict__ fo3_b,
    const float* __restrict__ fc_w, const float* __restrict__ fc_b,
    const _Float16* __restrict__ WT, float* __restrict__ out) {
  __shared__ _Float16 sC[16 * 168];
  __shared__ _Float16 sHa[16 * PITCH];
  __shared__ _Float16 sHb[16 * PITCH];
  __shared__ float sPool[64];
  int tid = threadIdx.x;
  int b = blockIdx.x >> 2, r0 = (blockIdx.x & 3) << 4;
  for (int i = tid; i < 16 * 32; i += 256) {
    int row = i >> 5, p = i & 31;
    sC[row * 168 + p] = (_Float16)x[b * (PP * NN) + p * 64 + r0 + row];
  }
  for (int i = tid; i < 16 * 16; i += 256) {
    int row = i >> 4, d4 = i & 15;
    float4 vpp = *(const float4*)(&Epp[(b * NN + r0 + row) * DE + d4 * 4]);
    float4 vpv = *(const float4*)(&Epv[(b * NN + r0 + row) * DE + d4 * 4]);
    half4v hpp, hpv;
    hpp[0] = (_Float16)vpp.x; hpp[1] = (_Float16)vpp.y;
    hpp[2] = (_Float16)vpp.z; hpp[3] = (_Float16)vpp.w;
    hpv[0] = (_Float16)vpv.x; hpv[1] = (_Float16)vpv.y;
    hpv[2] = (_Float16)vpv.z; hpv[3] = (_Float16)vpv.w;
    *(half4v*)(&sC[row * 168 + 32 + d4 * 4]) = hpp;
    *(half4v*)(&sC[row * 168 + 96 + d4 * 4]) = hpv;
  }
  __syncthreads();
  int lane = tid & 63, wv = tid >> 6;
  int c = lane & 15, q = lane >> 4;
  // fo1 (K=160), transposed-C; wave owns cols wv*32..+31
  half8 cf[5];
#pragma unroll
  for (int ks = 0; ks < 5; ks++)
    cf[ks] = *(const half8*)(&sC[c * 168 + ks * 32 + q * 8]);
#pragma unroll
  for (int nt2 = 0; nt2 < 2; nt2++) {
    int nt = wv * 2 + nt2;
    floatx4 a0 = {0.f, 0.f, 0.f, 0.f};
#pragma unroll
    for (int ks = 0; ks < 5; ks++) {
      half8 wf = *(const half8*)(&WT[OFF_FO1 + ((nt * 5 + ks) << 9) + (lane << 3)]);
      a0 = MFMA(wf, cf[ks], a0);
    }
    float4 bb = *(const float4*)(&fo1_b[nt * 16 + q * 4]);
    half4v h0;
    h0[0] = (_Float16)fmaxf(a0[0] + bb.x, 0.f);
    h0[1] = (_Float16)fmaxf(a0[1] + bb.y, 0.f);
    h0[2] = (_Float16)fmaxf(a0[2] + bb.z, 0.f);
    h0[3] = (_Float16)fmaxf(a0[3] + bb.w, 0.f);
    *(half4v*)(&sHa[c * PITCH + nt * 16 + q * 4]) = h0;
  }
  __syncthreads();
  // fo2 (K=128), transposed-C
  half8 g1[4];
#pragma unroll
  for (int ks = 0; ks < 4; ks++)
    g1[ks] = *(const half8*)(&sHa[c * PITCH + ks * 32 + q * 8]);
#pragma unroll
  for (int nt2 = 0; nt2 < 2; nt2++) {
    int nt = wv * 2 + nt2;
    floatx4 a0 = {0.f, 0.f, 0.f, 0.f};
#pragma unroll
    for (int ks = 0; ks < 4; ks++) {
      half8 wf = *(const half8*)(&WT[OFF_FO2 + ((nt * 4 + ks) << 9) + (lane << 3)]);
      a0 = MFMA(wf, g1[ks], a0);
    }
    float4 bb = *(const float4*)(&fo2_b[nt * 16 + q * 4]);
    half4v h0;
    h0[0] = (_Float16)fmaxf(a0[0] + bb.x, 0.f);
    h0[1] = (_Float16)fmaxf(a0[1] + bb.y, 0.f);
    h0[2] = (_Float16)fmaxf(a0[2] + bb.z, 0.f);
    h0[3] = (_Float16)fmaxf(a0[3] + bb.w, 0.f);
    *(half4v*)(&sHb[c * PITCH + nt * 16 + q * 4]) = h0;
  }
  __syncthreads();
  // fo3 (N=64): wave owns 16 cols; pool over the 16 real nodes
  half8 g2[4];
#pragma unroll
  for (int ks = 0; ks < 4; ks++)
    g2[ks] = *(const half8*)(&sHb[c * PITCH + ks * 32 + q * 8]);
  floatx4 e0 = {0.f, 0.f, 0.f, 0.f};
#pragma unroll
  for (int ks = 0; ks < 4; ks++) {
    half8 wf = *(const half8*)(&WT[OFF_FO3 + ((wv * 4 + ks) << 9) + (lane << 3)]);
    e0 = MFMA(g2[ks], wf, e0);
  }
  float bb3 = fo3_b[wv * 16 + c];
  float s = 0.f;
#pragma unroll
  for (int rg = 0; rg < 4; rg++) s += fmaxf(e0[rg] + bb3, 0.f);
  s += __shfl_xor(s, 16);
  s += __shfl_xor(s, 32);
  if (lane < 16) sPool[wv * 16 + c] = s;
  __syncthreads();
  if (tid < NCLS) {
    float o = ((blockIdx.x & 3) == 0) ? fc_b[tid] : 0.f;
#pragma unroll
    for (int d = 0; d < 64; d++) o += sPool[d] * fc_w[d * NCLS + tid];
    atomicAdd(&out[b * NCLS + tid], o);
  }
}

extern "C" void kernel_launch(void* const* d_in, const int* in_sizes, int n_in,
                              void* d_out, int out_size, void* d_ws, size_t ws_size,
                              hipStream_t stream) {
  const float* x = (const float*)d_in[0];
  const float* y = (const float*)d_in[1];
  const float* fr1_w = (const float*)d_in[2];  const float* fr1_b = (const float*)d_in[3];
  const float* fr2_w = (const float*)d_in[4];  const float* fr2_b = (const float*)d_in[5];
  const float* fr3_w = (const float*)d_in[6];  const float* fr3_b = (const float*)d_in[7];
  const float* fr1pv_w = (const float*)d_in[8];  const float* fr1pv_b = (const float*)d_in[9];
  const float* fr2pv_w = (const float*)d_in[10]; const float* fr2pv_b = (const float*)d_in[11];
  const float* fr3pv_w = (const float*)d_in[12]; const float* fr3pv_b = (const float*)d_in[13];
  const float* fo1_w = (const float*)d_in[14];  const float* fo1_b = (const float*)d_in[15];
  const float* fo2_w = (const float*)d_in[16];  const float* fo2_b = (const float*)d_in[17];
  const float* fo3_w = (const float*)d_in[18];  const float* fo3_b = (const float*)d_in[19];
  const float* fc_w = (const float*)d_in[20];   const float* fc_b = (const float*)d_in[21];

  char* ws = (char*)d_ws;
  _Float16* A1h   = (_Float16*)(ws);                 // [128][64][128] fp16 (bias folded)
  _Float16* B1h   = (_Float16*)(ws + (2u << 20));
  _Float16* A1pvh = (_Float16*)(ws + (4u << 20));    // (bias folded)
  _Float16* B1pvh = (_Float16*)(ws + (6u << 20));    // [128][14][128] fp16
  _Float16* WT    = (_Float16*)(ws + (7u << 20));    // frag-major fp16 weights (~200 KB)
  float* Epp      = (float*)(ws + (8u << 20));       // [128][64][64] f32
  float* Epv      = (float*)(ws + (10u << 20));      // [128][64][64] f32

  k0_prep<<<926, 256, 0, stream>>>(x, y, fr1_w, fr1_b, fr1pv_w, fr1pv_b,
                                   fr2_w, fr3_w, fr2pv_w, fr3pv_w,
                                   fo1_w, fo2_w, fo3_w,
                                   A1h, B1h, A1pvh, B1pvh, WT, (float*)d_out);
  edge_fused<<<EGRID3, 256, 0, stream>>>(A1h, B1h, A1pvh, B1pvh,
                                         fr2_b, fr3_b, fr2pv_b, fr3pv_b,
                                         WT, Epp, Epv);
  node_out<<<NB * 4, 256, 0, stream>>>(x, Epp, Epv, fo1_b, fo2_b, fo3_b,
                                       fc_w, fc_b, WT, (float*)d_out);
}